// Round 5
// baseline (139.981 us; speedup 1.0000x reference)
//
#include <hip/hip_runtime.h>
#include <hip/hip_bf16.h>

typedef __attribute__((ext_vector_type(8))) __bf16 bf16x8;
typedef __attribute__((ext_vector_type(4))) float f32x4;

__device__ __forceinline__ unsigned short f2bf(float f) {
  unsigned int u = __builtin_bit_cast(unsigned int, f);
  u += 0x7fffu + ((u >> 16) & 1u);   // RNE
  return (unsigned short)(u >> 16);
}

__device__ __forceinline__ void gll16(const void* g, void* l) {
  __builtin_amdgcn_global_load_lds(
      (const __attribute__((address_space(1))) void*)g,
      (__attribute__((address_space(3))) void*)l, 16, 0, 0);
}

// read a 16B MFMA fragment from an LDS tile with 128B rows, XOR-swizzled
__device__ __forceinline__ bf16x8 lds_frag(const unsigned short* base, int row, int kbyte) {
  int off = row * 128 + (kbyte ^ ((row & 7) << 4));
  return *(const bf16x8*)((const char*)base + off);
}

// ---------------- converts ----------------
__global__ __launch_bounds__(256) void cast_bf16(const float* __restrict__ in,
                                                 unsigned short* __restrict__ out, int n) {
  int i = (blockIdx.x * 256 + threadIdx.x) * 4;
  if (i < n) {
    float4 v = *(const float4*)(in + i);
    ushort4 o;
    o.x = f2bf(v.x); o.y = f2bf(v.y); o.z = f2bf(v.z); o.w = f2bf(v.w);
    *(ushort4*)(out + i) = o;
  }
}

// in [K][N] f32 -> out [N][K] bf16
__global__ __launch_bounds__(256) void transpose_cast(const float* __restrict__ in,
                                                      unsigned short* __restrict__ out,
                                                      int K, int N) {
  __shared__ float tile[32][33];
  int nb = N >> 5;
  int bx = blockIdx.x % nb, by = blockIdx.x / nb;
  int n0 = bx << 5, k0 = by << 5;
  int c = threadIdx.x & 31, r0 = threadIdx.x >> 5;
#pragma unroll
  for (int i = 0; i < 4; ++i) {
    int r = r0 + i * 8;
    tile[r][c] = in[(size_t)(k0 + r) * N + n0 + c];
  }
  __syncthreads();
#pragma unroll
  for (int i = 0; i < 4; ++i) {
    int r = r0 + i * 8;
    out[(size_t)(n0 + r) * K + k0 + c] = f2bf(tile[c][r]);
  }
}

// ---------------- QKV GEMM: 256x256 tile, 8 waves, STATIC double buffer ----
// C = A[4096,1024] * Bt[3072,1024]^T + bias, scattered to Q/K/Vt bf16.
// Static A0/B0/A1/B1 so alias analysis can prove stage-writes are disjoint
// from compute's ds_reads -> no compiler-injected vmcnt(0) before ds_read.
__global__ __launch_bounds__(512, 2) void gemm_qkv256(
    const unsigned short* __restrict__ A, const unsigned short* __restrict__ Bt,
    const float* __restrict__ bias,
    unsigned short* __restrict__ Qg, unsigned short* __restrict__ Kg,
    unsigned short* __restrict__ Vtg, int K) {
  __shared__ unsigned short A0[256 * 64], B0[256 * 64];
  __shared__ unsigned short A1[256 * 64], B1[256 * 64];
  const int t = threadIdx.x;
  const int l = t & 63, lr = l & 15, hi = l >> 4;
  const int w = t >> 6;
  const int wr = w >> 2, wc = w & 3;           // 2M x 4N waves
  const int bm = blockIdx.x / 12, bn = blockIdx.x % 12;
  const int m0 = bm << 8, n0 = bn << 8;
  const int wbase = (t & ~63) * 8;             // wave chunk base (ushorts)

  f32x4 acc[8][4] = {};

  auto stage = [&](int kt, unsigned short* Ad, unsigned short* Bd) {
    const unsigned short* Ab = A + (size_t)m0 * K + kt * 64;
    const unsigned short* Bb = Bt + (size_t)n0 * K + kt * 64;
#pragma unroll
    for (int i = 0; i < 4; ++i) {
      int ci = i * 512 + t;
      int row = ci >> 3, cpos = ci & 7;
      int c = cpos ^ (row & 7);                // pre-swizzled global source
      gll16(Ab + (size_t)row * K + c * 8, Ad + i * 4096 + wbase);
      gll16(Bb + (size_t)row * K + c * 8, Bd + i * 4096 + wbase);
    }
  };

  auto compute = [&](const unsigned short* Ad, const unsigned short* Bd) {
#pragma unroll
    for (int ks = 0; ks < 2; ++ks) {
      bf16x8 af[8], bv[4];
#pragma unroll
      for (int mi = 0; mi < 8; ++mi)
        af[mi] = lds_frag(Ad, wr * 128 + mi * 16 + lr, ks * 64 + hi * 16);
#pragma unroll
      for (int ni = 0; ni < 4; ++ni)
        bv[ni] = lds_frag(Bd, wc * 64 + ni * 16 + lr, ks * 64 + hi * 16);
      __builtin_amdgcn_s_setprio(1);
#pragma unroll
      for (int mi = 0; mi < 8; ++mi)
#pragma unroll
        for (int ni = 0; ni < 4; ++ni)
          acc[mi][ni] = __builtin_amdgcn_mfma_f32_16x16x32_bf16(af[mi], bv[ni], acc[mi][ni], 0, 0, 0);
      __builtin_amdgcn_s_setprio(0);
    }
  };

  const int nt = K >> 6;                       // 16
  stage(0, A0, B0);
  __syncthreads();
  for (int kt = 0; kt < nt; kt += 2) {
    if (kt + 1 < nt) stage(kt + 1, A1, B1);    // issue into buf1 (disjoint, static)
    compute(A0, B0);
    __syncthreads();                           // drains buf1 loads (issued ~full compute ago)
    if (kt + 2 < nt) stage(kt + 2, A0, B0);
    if (kt + 1 < nt) {
      compute(A1, B1);
      __syncthreads();
    }
  }

#pragma unroll
  for (int mi = 0; mi < 8; ++mi)
#pragma unroll
    for (int ni = 0; ni < 4; ++ni)
#pragma unroll
      for (int r = 0; r < 4; ++r) {
        int m = m0 + wr * 128 + mi * 16 + 4 * hi + r;
        int n = n0 + wc * 64 + ni * 16 + lr;
        float v = acc[mi][ni][r] + bias[n];
        int b = m >> 10, s = m & 1023;
        int which = n >> 10, d = n & 1023;
        int h = d >> 6, di = d & 63;
        int bh = (b << 4) + h;
        if (which == 0)      Qg[((size_t)(bh << 10) + s) * 64 + di] = f2bf(v * 0.125f);
        else if (which == 1) Kg[((size_t)(bh << 10) + s) * 64 + di] = f2bf(v);
        else                 Vtg[((size_t)(bh << 6) + di) * 1024 + s] = f2bf(v);
      }
}

// ---------------- proj GEMM: 128x128 tile, 4 waves, STATIC double buffer ----
__global__ __launch_bounds__(256) void gemm_proj128(
    const unsigned short* __restrict__ A, const unsigned short* __restrict__ Bt,
    const float* __restrict__ bias, float* __restrict__ outf,
    int M, int N, int K) {
  __shared__ unsigned short A0[128 * 64], B0[128 * 64];
  __shared__ unsigned short A1[128 * 64], B1[128 * 64];
  const int t = threadIdx.x;
  const int w = t >> 6, l = t & 63, lr = l & 15, hi = l >> 4;
  const int wr = w >> 1, wc = w & 1;
  const int nbn = N >> 7;
  const int bm = blockIdx.x / nbn, bn = blockIdx.x % nbn;
  const int m0 = bm << 7, n0 = bn << 7;
  const int wbase = (t & ~63) * 8;

  f32x4 acc[4][4] = {};

  auto stage = [&](int kt, unsigned short* Ad, unsigned short* Bd) {
    const unsigned short* Ab = A + (size_t)m0 * K + kt * 64;
    const unsigned short* Bb = Bt + (size_t)n0 * K + kt * 64;
#pragma unroll
    for (int i = 0; i < 4; ++i) {
      int ci = i * 256 + t;
      int row = ci >> 3, cpos = ci & 7;
      int c = cpos ^ (row & 7);
      gll16(Ab + (size_t)row * K + c * 8, Ad + i * 2048 + wbase);
      gll16(Bb + (size_t)row * K + c * 8, Bd + i * 2048 + wbase);
    }
  };

  auto compute = [&](const unsigned short* Ad, const unsigned short* Bd) {
#pragma unroll
    for (int ks = 0; ks < 2; ++ks) {
      bf16x8 af[4], bv[4];
#pragma unroll
      for (int mi = 0; mi < 4; ++mi)
        af[mi] = lds_frag(Ad, wr * 64 + mi * 16 + lr, ks * 64 + hi * 16);
#pragma unroll
      for (int ni = 0; ni < 4; ++ni)
        bv[ni] = lds_frag(Bd, wc * 64 + ni * 16 + lr, ks * 64 + hi * 16);
      __builtin_amdgcn_s_setprio(1);
#pragma unroll
      for (int mi = 0; mi < 4; ++mi)
#pragma unroll
        for (int ni = 0; ni < 4; ++ni)
          acc[mi][ni] = __builtin_amdgcn_mfma_f32_16x16x32_bf16(af[mi], bv[ni], acc[mi][ni], 0, 0, 0);
      __builtin_amdgcn_s_setprio(0);
    }
  };

  const int nt = K >> 6;
  stage(0, A0, B0);
  __syncthreads();
  for (int kt = 0; kt < nt; kt += 2) {
    if (kt + 1 < nt) stage(kt + 1, A1, B1);
    compute(A0, B0);
    __syncthreads();
    if (kt + 2 < nt) stage(kt + 2, A0, B0);
    if (kt + 1 < nt) {
      compute(A1, B1);
      __syncthreads();
    }
  }

#pragma unroll
  for (int mi = 0; mi < 4; ++mi)
#pragma unroll
    for (int ni = 0; ni < 4; ++ni)
#pragma unroll
      for (int r = 0; r < 4; ++r) {
        int m = m0 + wr * 64 + mi * 16 + 4 * hi + r;
        int n = n0 + wc * 64 + ni * 16 + lr;
        outf[(size_t)m * N + n] = acc[mi][ni][r] + bias[n];
      }
}

// ---------------- causal flash attention (unchanged this round) ----------------
__global__ __launch_bounds__(256) void attn_kernel(
    const unsigned short* __restrict__ Qg, const unsigned short* __restrict__ Kg,
    const unsigned short* __restrict__ Vtg, unsigned short* __restrict__ Og) {
  __shared__ unsigned short Klds[2][64 * 64];
  __shared__ unsigned short Vlds[2][64 * 64];
  __shared__ __align__(16) unsigned short Plds[4][16][72];  // padded rows: 144B
  const int bh = blockIdx.x & 63;
  const int qt = blockIdx.x >> 6;
  const int t = threadIdx.x;
  const int w = t >> 6, l = t & 63, lr = l & 15, hi = l >> 4;
  const unsigned short* Qbh = Qg + (size_t)bh * 65536;
  const unsigned short* Kbh = Kg + (size_t)bh * 65536;
  const unsigned short* Vbh = Vtg + (size_t)bh * 65536;
  const int q0 = qt * 64 + w * 16;
  const int wbase = (t & ~63) * 8;
  const float LOG2E = 1.4426950408889634f;

  bf16x8 qf[2];
#pragma unroll
  for (int ks = 0; ks < 2; ++ks)
    qf[ks] = *(const bf16x8*)(Qbh + (size_t)(q0 + lr) * 64 + ks * 32 + hi * 8);

  f32x4 oc[4] = {};
  float mrun[4], lrun[4];
#pragma unroll
  for (int r = 0; r < 4; ++r) { mrun[r] = -1e30f; lrun[r] = 0.f; }

  auto stage = [&](int kt, int b) {
#pragma unroll
    for (int i = 0; i < 2; ++i) {
      int ci = i * 256 + t;
      int row = ci >> 3, cpos = ci & 7;
      int c = cpos ^ (row & 7);
      gll16(Kbh + (size_t)(kt * 64 + row) * 64 + c * 8, &Klds[b][i * 2048 + wbase]);
      gll16(Vbh + (size_t)row * 1024 + kt * 64 + c * 8, &Vlds[b][i * 2048 + wbase]);
    }
  };

  stage(0, 0);
  __syncthreads();

  for (int kt = 0; kt <= qt; ++kt) {
    const int cur = kt & 1;
    if (kt < qt) stage(kt + 1, cur ^ 1);

    f32x4 sc[4] = {};
    __builtin_amdgcn_s_setprio(1);
#pragma unroll
    for (int c = 0; c < 4; ++c)
#pragma unroll
      for (int ks = 0; ks < 2; ++ks) {
        bf16x8 kf = lds_frag(&Klds[cur][0], c * 16 + lr, ks * 64 + hi * 16);
        sc[c] = __builtin_amdgcn_mfma_f32_16x16x32_bf16(qf[ks], kf, sc[c], 0, 0, 0);
      }
    __builtin_amdgcn_s_setprio(0);
    if (kt == qt) {
#pragma unroll
      for (int c = 0; c < 4; ++c)
#pragma unroll
        for (int r = 0; r < 4; ++r)
          if (c * 16 + lr > w * 16 + 4 * hi + r) sc[c][r] = -1e30f;
    }

    float pv[4][4];
#pragma unroll
    for (int r = 0; r < 4; ++r) {
      float mx = fmaxf(fmaxf(sc[0][r], sc[1][r]), fmaxf(sc[2][r], sc[3][r]));
#pragma unroll
      for (int d = 1; d < 16; d <<= 1) mx = fmaxf(mx, __shfl_xor(mx, d));
      float mn = fmaxf(mrun[r], mx);
      float al = exp2f((mrun[r] - mn) * LOG2E);
      mrun[r] = mn;
      float s = 0.f;
#pragma unroll
      for (int c = 0; c < 4; ++c) {
        float p = exp2f((sc[c][r] - mn) * LOG2E);
        pv[c][r] = p;
        s += p;
      }
#pragma unroll
      for (int d = 1; d < 16; d <<= 1) s += __shfl_xor(s, d);
      lrun[r] = lrun[r] * al + s;
#pragma unroll
      for (int c = 0; c < 4; ++c) oc[c][r] *= al;
    }

#pragma unroll
    for (int c = 0; c < 4; ++c)
#pragma unroll
      for (int r = 0; r < 4; ++r)
        Plds[w][4 * hi + r][c * 16 + lr] = f2bf(pv[c][r]);
    asm volatile("s_waitcnt lgkmcnt(0)" ::: "memory");
    __builtin_amdgcn_sched_barrier(0);

    bf16x8 pa[2];
#pragma unroll
    for (int ks = 0; ks < 2; ++ks)
      pa[ks] = *(const bf16x8*)(&Plds[w][lr][ks * 32 + hi * 8]);
    __builtin_amdgcn_s_setprio(1);
#pragma unroll
    for (int c = 0; c < 4; ++c)
#pragma unroll
      for (int ks = 0; ks < 2; ++ks) {
        bf16x8 vf = lds_frag(&Vlds[cur][0], c * 16 + lr, ks * 64 + hi * 16);
        oc[c] = __builtin_amdgcn_mfma_f32_16x16x32_bf16(pa[ks], vf, oc[c], 0, 0, 0);
      }
    __builtin_amdgcn_s_setprio(0);
    __syncthreads();
  }

  const int b = bh >> 4, h = bh & 15;
#pragma unroll
  for (int r = 0; r < 4; ++r) {
    float inv = 1.0f / lrun[r];
    int q = qt * 64 + w * 16 + 4 * hi + r;
    size_t rowbase = ((size_t)(b * 1024 + q)) * 1024 + h * 64;
#pragma unroll
    for (int c = 0; c < 4; ++c)
      Og[rowbase + c * 16 + lr] = f2bf(oc[c][r] * inv);
  }
}

extern "C" void kernel_launch(void* const* d_in, const int* in_sizes, int n_in,
                              void* d_out, int out_size, void* d_ws, size_t ws_size,
                              hipStream_t stream) {
  const float* x      = (const float*)d_in[0];
  const float* w_attn = (const float*)d_in[1];
  const float* b_attn = (const float*)d_in[2];
  const float* w_proj = (const float*)d_in[3];
  const float* b_proj = (const float*)d_in[4];
  float* out = (float*)d_out;

  unsigned short* ws  = (unsigned short*)d_ws;
  unsigned short* xb  = ws;                       // [4096,1024] bf16 (reused as Og)
  unsigned short* waT = xb + 4096 * 1024;         // [3072,1024] bf16
  unsigned short* wpT = waT + 3072 * 1024;        // [1024,1024] bf16
  unsigned short* Qg  = wpT + 1024 * 1024;        // [64,1024,64]
  unsigned short* Kg  = Qg + 4194304;             // [64,1024,64]
  unsigned short* Vtg = Kg + 4194304;             // [64,64,1024]
  unsigned short* Og  = xb;                       // alias (x consumed by then)

  cast_bf16<<<4096, 256, 0, stream>>>(x, xb, 4194304);
  transpose_cast<<<(3072 / 32) * (1024 / 32), 256, 0, stream>>>(w_attn, waT, 1024, 3072);
  transpose_cast<<<(1024 / 32) * (1024 / 32), 256, 0, stream>>>(w_proj, wpT, 1024, 1024);

  gemm_qkv256<<<16 * 12, 512, 0, stream>>>(xb, waT, b_attn, Qg, Kg, Vtg, 1024);
  attn_kernel<<<1024, 256, 0, stream>>>(Qg, Kg, Vtg, Og);
  gemm_proj128<<<32 * 8, 256, 0, stream>>>(Og, wpT, b_proj, (float*)out, 4096, 1024, 1024);
}

// Round 6
// 139.897 us; speedup vs baseline: 1.0006x; 1.0006x over previous
//
#include <hip/hip_runtime.h>
#include <hip/hip_bf16.h>

typedef __attribute__((ext_vector_type(8))) __bf16 bf16x8;
typedef __attribute__((ext_vector_type(4))) float f32x4;

__device__ __forceinline__ unsigned short f2bf(float f) {
  unsigned int u = __builtin_bit_cast(unsigned int, f);
  u += 0x7fffu + ((u >> 16) & 1u);   // RNE
  return (unsigned short)(u >> 16);
}

__device__ __forceinline__ void gll16(const void* g, void* l) {
  __builtin_amdgcn_global_load_lds(
      (const __attribute__((address_space(1))) void*)g,
      (__attribute__((address_space(3))) void*)l, 16, 0, 0);
}

// read a 16B MFMA fragment from an LDS tile with 128B rows, XOR-swizzled
__device__ __forceinline__ bf16x8 lds_frag(const unsigned short* base, int row, int kbyte) {
  int off = row * 128 + (kbyte ^ ((row & 7) << 4));
  return *(const bf16x8*)((const char*)base + off);
}

// ---------------- converts ----------------
__global__ __launch_bounds__(256) void cast_bf16(const float* __restrict__ in,
                                                 unsigned short* __restrict__ out, int n) {
  int i = (blockIdx.x * 256 + threadIdx.x) * 4;
  if (i < n) {
    float4 v = *(const float4*)(in + i);
    ushort4 o;
    o.x = f2bf(v.x); o.y = f2bf(v.y); o.z = f2bf(v.z); o.w = f2bf(v.w);
    *(ushort4*)(out + i) = o;
  }
}

// in [K][N] f32 -> out [N][K] bf16
__global__ __launch_bounds__(256) void transpose_cast(const float* __restrict__ in,
                                                      unsigned short* __restrict__ out,
                                                      int K, int N) {
  __shared__ float tile[32][33];
  int nb = N >> 5;
  int bx = blockIdx.x % nb, by = blockIdx.x / nb;
  int n0 = bx << 5, k0 = by << 5;
  int c = threadIdx.x & 31, r0 = threadIdx.x >> 5;
#pragma unroll
  for (int i = 0; i < 4; ++i) {
    int r = r0 + i * 8;
    tile[r][c] = in[(size_t)(k0 + r) * N + n0 + c];
  }
  __syncthreads();
#pragma unroll
  for (int i = 0; i < 4; ++i) {
    int r = r0 + i * 8;
    out[(size_t)(n0 + r) * K + k0 + c] = f2bf(tile[c][r]);
  }
}

// ---------------- QKV GEMM: 256x256 tile, 8 waves, STATIC double buffer ----
// C = A[4096,1024] * Bt[3072,1024]^T + bias, scattered to Q/K/Vt bf16.
// Static A0/B0/A1/B1 so alias analysis can prove stage-writes are disjoint
// from compute's ds_reads -> no compiler-injected vmcnt(0) before ds_read.
__global__ __launch_bounds__(512, 2) void gemm_qkv256(
    const unsigned short* __restrict__ A, const unsigned short* __restrict__ Bt,
    const float* __restrict__ bias,
    unsigned short* __restrict__ Qg, unsigned short* __restrict__ Kg,
    unsigned short* __restrict__ Vtg, int K) {
  __shared__ unsigned short A0[256 * 64], B0[256 * 64];
  __shared__ unsigned short A1[256 * 64], B1[256 * 64];
  const int t = threadIdx.x;
  const int l = t & 63, lr = l & 15, hi = l >> 4;
  const int w = t >> 6;
  const int wr = w >> 2, wc = w & 3;           // 2M x 4N waves
  const int bm = blockIdx.x / 12, bn = blockIdx.x % 12;
  const int m0 = bm << 8, n0 = bn << 8;
  const int wbase = (t & ~63) * 8;             // wave chunk base (ushorts)

  f32x4 acc[8][4] = {};

  auto stage = [&](int kt, unsigned short* Ad, unsigned short* Bd) {
    const unsigned short* Ab = A + (size_t)m0 * K + kt * 64;
    const unsigned short* Bb = Bt + (size_t)n0 * K + kt * 64;
#pragma unroll
    for (int i = 0; i < 4; ++i) {
      int ci = i * 512 + t;
      int row = ci >> 3, cpos = ci & 7;
      int c = cpos ^ (row & 7);                // pre-swizzled global source
      gll16(Ab + (size_t)row * K + c * 8, Ad + i * 4096 + wbase);
      gll16(Bb + (size_t)row * K + c * 8, Bd + i * 4096 + wbase);
    }
  };

  auto compute = [&](const unsigned short* Ad, const unsigned short* Bd) {
#pragma unroll
    for (int ks = 0; ks < 2; ++ks) {
      bf16x8 af[8], bv[4];
#pragma unroll
      for (int mi = 0; mi < 8; ++mi)
        af[mi] = lds_frag(Ad, wr * 128 + mi * 16 + lr, ks * 64 + hi * 16);
#pragma unroll
      for (int ni = 0; ni < 4; ++ni)
        bv[ni] = lds_frag(Bd, wc * 64 + ni * 16 + lr, ks * 64 + hi * 16);
      __builtin_amdgcn_s_setprio(1);
#pragma unroll
      for (int mi = 0; mi < 8; ++mi)
#pragma unroll
        for (int ni = 0; ni < 4; ++ni)
          acc[mi][ni] = __builtin_amdgcn_mfma_f32_16x16x32_bf16(af[mi], bv[ni], acc[mi][ni], 0, 0, 0);
      __builtin_amdgcn_s_setprio(0);
    }
  };

  const int nt = K >> 6;                       // 16
  stage(0, A0, B0);
  __syncthreads();
  for (int kt = 0; kt < nt; kt += 2) {
    if (kt + 1 < nt) stage(kt + 1, A1, B1);    // issue into buf1 (disjoint, static)
    compute(A0, B0);
    __syncthreads();                           // drains buf1 loads (issued ~full compute ago)
    if (kt + 2 < nt) stage(kt + 2, A0, B0);
    if (kt + 1 < nt) {
      compute(A1, B1);
      __syncthreads();
    }
  }

#pragma unroll
  for (int mi = 0; mi < 8; ++mi)
#pragma unroll
    for (int ni = 0; ni < 4; ++ni)
#pragma unroll
      for (int r = 0; r < 4; ++r) {
        int m = m0 + wr * 128 + mi * 16 + 4 * hi + r;
        int n = n0 + wc * 64 + ni * 16 + lr;
        float v = acc[mi][ni][r] + bias[n];
        int b = m >> 10, s = m & 1023;
        int which = n >> 10, d = n & 1023;
        int h = d >> 6, di = d & 63;
        int bh = (b << 4) + h;
        if (which == 0)      Qg[((size_t)(bh << 10) + s) * 64 + di] = f2bf(v * 0.125f);
        else if (which == 1) Kg[((size_t)(bh << 10) + s) * 64 + di] = f2bf(v);
        else                 Vtg[((size_t)(bh << 6) + di) * 1024 + s] = f2bf(v);
      }
}

// ---------------- proj GEMM: 128x128 tile, 4 waves, STATIC double buffer ----
__global__ __launch_bounds__(256) void gemm_proj128(
    const unsigned short* __restrict__ A, const unsigned short* __restrict__ Bt,
    const float* __restrict__ bias, float* __restrict__ outf,
    int M, int N, int K) {
  __shared__ unsigned short A0[128 * 64], B0[128 * 64];
  __shared__ unsigned short A1[128 * 64], B1[128 * 64];
  const int t = threadIdx.x;
  const int w = t >> 6, l = t & 63, lr = l & 15, hi = l >> 4;
  const int wr = w >> 1, wc = w & 1;
  const int nbn = N >> 7;
  const int bm = blockIdx.x / nbn, bn = blockIdx.x % nbn;
  const int m0 = bm << 7, n0 = bn << 7;
  const int wbase = (t & ~63) * 8;

  f32x4 acc[4][4] = {};

  auto stage = [&](int kt, unsigned short* Ad, unsigned short* Bd) {
    const unsigned short* Ab = A + (size_t)m0 * K + kt * 64;
    const unsigned short* Bb = Bt + (size_t)n0 * K + kt * 64;
#pragma unroll
    for (int i = 0; i < 4; ++i) {
      int ci = i * 256 + t;
      int row = ci >> 3, cpos = ci & 7;
      int c = cpos ^ (row & 7);
      gll16(Ab + (size_t)row * K + c * 8, Ad + i * 2048 + wbase);
      gll16(Bb + (size_t)row * K + c * 8, Bd + i * 2048 + wbase);
    }
  };

  auto compute = [&](const unsigned short* Ad, const unsigned short* Bd) {
#pragma unroll
    for (int ks = 0; ks < 2; ++ks) {
      bf16x8 af[4], bv[4];
#pragma unroll
      for (int mi = 0; mi < 4; ++mi)
        af[mi] = lds_frag(Ad, wr * 64 + mi * 16 + lr, ks * 64 + hi * 16);
#pragma unroll
      for (int ni = 0; ni < 4; ++ni)
        bv[ni] = lds_frag(Bd, wc * 64 + ni * 16 + lr, ks * 64 + hi * 16);
      __builtin_amdgcn_s_setprio(1);
#pragma unroll
      for (int mi = 0; mi < 4; ++mi)
#pragma unroll
        for (int ni = 0; ni < 4; ++ni)
          acc[mi][ni] = __builtin_amdgcn_mfma_f32_16x16x32_bf16(af[mi], bv[ni], acc[mi][ni], 0, 0, 0);
      __builtin_amdgcn_s_setprio(0);
    }
  };

  const int nt = K >> 6;
  stage(0, A0, B0);
  __syncthreads();
  for (int kt = 0; kt < nt; kt += 2) {
    if (kt + 1 < nt) stage(kt + 1, A1, B1);
    compute(A0, B0);
    __syncthreads();
    if (kt + 2 < nt) stage(kt + 2, A0, B0);
    if (kt + 1 < nt) {
      compute(A1, B1);
      __syncthreads();
    }
  }

#pragma unroll
  for (int mi = 0; mi < 4; ++mi)
#pragma unroll
    for (int ni = 0; ni < 4; ++ni)
#pragma unroll
      for (int r = 0; r < 4; ++r) {
        int m = m0 + wr * 64 + mi * 16 + 4 * hi + r;
        int n = n0 + wc * 64 + ni * 16 + lr;
        outf[(size_t)m * N + n] = acc[mi][ni][r] + bias[n];
      }
}

// ---------------- causal flash attention (unchanged this round) ----------------
__global__ __launch_bounds__(256) void attn_kernel(
    const unsigned short* __restrict__ Qg, const unsigned short* __restrict__ Kg,
    const unsigned short* __restrict__ Vtg, unsigned short* __restrict__ Og) {
  __shared__ unsigned short Klds[2][64 * 64];
  __shared__ unsigned short Vlds[2][64 * 64];
  __shared__ __align__(16) unsigned short Plds[4][16][72];  // padded rows: 144B
  const int bh = blockIdx.x & 63;
  const int qt = blockIdx.x >> 6;
  const int t = threadIdx.x;
  const int w = t >> 6, l = t & 63, lr = l & 15, hi = l >> 4;
  const unsigned short* Qbh = Qg + (size_t)bh * 65536;
  const unsigned short* Kbh = Kg + (size_t)bh * 65536;
  const unsigned short* Vbh = Vtg + (size_t)bh * 65536;
  const int q0 = qt * 64 + w * 16;
  const int wbase = (t & ~63) * 8;
  const float LOG2E = 1.4426950408889634f;

  bf16x8 qf[2];
#pragma unroll
  for (int ks = 0; ks < 2; ++ks)
    qf[ks] = *(const bf16x8*)(Qbh + (size_t)(q0 + lr) * 64 + ks * 32 + hi * 8);

  f32x4 oc[4] = {};
  float mrun[4], lrun[4];
#pragma unroll
  for (int r = 0; r < 4; ++r) { mrun[r] = -1e30f; lrun[r] = 0.f; }

  auto stage = [&](int kt, int b) {
#pragma unroll
    for (int i = 0; i < 2; ++i) {
      int ci = i * 256 + t;
      int row = ci >> 3, cpos = ci & 7;
      int c = cpos ^ (row & 7);
      gll16(Kbh + (size_t)(kt * 64 + row) * 64 + c * 8, &Klds[b][i * 2048 + wbase]);
      gll16(Vbh + (size_t)row * 1024 + kt * 64 + c * 8, &Vlds[b][i * 2048 + wbase]);
    }
  };

  stage(0, 0);
  __syncthreads();

  for (int kt = 0; kt <= qt; ++kt) {
    const int cur = kt & 1;
    if (kt < qt) stage(kt + 1, cur ^ 1);

    f32x4 sc[4] = {};
    __builtin_amdgcn_s_setprio(1);
#pragma unroll
    for (int c = 0; c < 4; ++c)
#pragma unroll
      for (int ks = 0; ks < 2; ++ks) {
        bf16x8 kf = lds_frag(&Klds[cur][0], c * 16 + lr, ks * 64 + hi * 16);
        sc[c] = __builtin_amdgcn_mfma_f32_16x16x32_bf16(qf[ks], kf, sc[c], 0, 0, 0);
      }
    __builtin_amdgcn_s_setprio(0);
    if (kt == qt) {
#pragma unroll
      for (int c = 0; c < 4; ++c)
#pragma unroll
        for (int r = 0; r < 4; ++r)
          if (c * 16 + lr > w * 16 + 4 * hi + r) sc[c][r] = -1e30f;
    }

    float pv[4][4];
#pragma unroll
    for (int r = 0; r < 4; ++r) {
      float mx = fmaxf(fmaxf(sc[0][r], sc[1][r]), fmaxf(sc[2][r], sc[3][r]));
#pragma unroll
      for (int d = 1; d < 16; d <<= 1) mx = fmaxf(mx, __shfl_xor(mx, d));
      float mn = fmaxf(mrun[r], mx);
      float al = exp2f((mrun[r] - mn) * LOG2E);
      mrun[r] = mn;
      float s = 0.f;
#pragma unroll
      for (int c = 0; c < 4; ++c) {
        float p = exp2f((sc[c][r] - mn) * LOG2E);
        pv[c][r] = p;
        s += p;
      }
#pragma unroll
      for (int d = 1; d < 16; d <<= 1) s += __shfl_xor(s, d);
      lrun[r] = lrun[r] * al + s;
#pragma unroll
      for (int c = 0; c < 4; ++c) oc[c][r] *= al;
    }

#pragma unroll
    for (int c = 0; c < 4; ++c)
#pragma unroll
      for (int r = 0; r < 4; ++r)
        Plds[w][4 * hi + r][c * 16 + lr] = f2bf(pv[c][r]);
    asm volatile("s_waitcnt lgkmcnt(0)" ::: "memory");
    __builtin_amdgcn_sched_barrier(0);

    bf16x8 pa[2];
#pragma unroll
    for (int ks = 0; ks < 2; ++ks)
      pa[ks] = *(const bf16x8*)(&Plds[w][lr][ks * 32 + hi * 8]);
    __builtin_amdgcn_s_setprio(1);
#pragma unroll
    for (int c = 0; c < 4; ++c)
#pragma unroll
      for (int ks = 0; ks < 2; ++ks) {
        bf16x8 vf = lds_frag(&Vlds[cur][0], c * 16 + lr, ks * 64 + hi * 16);
        oc[c] = __builtin_amdgcn_mfma_f32_16x16x32_bf16(pa[ks], vf, oc[c], 0, 0, 0);
      }
    __builtin_amdgcn_s_setprio(0);
    __syncthreads();
  }

  const int b = bh >> 4, h = bh & 15;
#pragma unroll
  for (int r = 0; r < 4; ++r) {
    float inv = 1.0f / lrun[r];
    int q = qt * 64 + w * 16 + 4 * hi + r;
    size_t rowbase = ((size_t)(b * 1024 + q)) * 1024 + h * 64;
#pragma unroll
    for (int c = 0; c < 4; ++c)
      Og[rowbase + c * 16 + lr] = f2bf(oc[c][r] * inv);
  }
}

extern "C" void kernel_launch(void* const* d_in, const int* in_sizes, int n_in,
                              void* d_out, int out_size, void* d_ws, size_t ws_size,
                              hipStream_t stream) {
  const float* x      = (const float*)d_in[0];
  const float* w_attn = (const float*)d_in[1];
  const float* b_attn = (const float*)d_in[2];
  const float* w_proj = (const float*)d_in[3];
  const float* b_proj = (const float*)d_in[4];
  float* out = (float*)d_out;

  unsigned short* ws  = (unsigned short*)d_ws;
  unsigned short* xb  = ws;                       // [4096,1024] bf16 (reused as Og)
  unsigned short* waT = xb + 4096 * 1024;         // [3072,1024] bf16
  unsigned short* wpT = waT + 3072 * 1024;        // [1024,1024] bf16
  unsigned short* Qg  = wpT + 1024 * 1024;        // [64,1024,64]
  unsigned short* Kg  = Qg + 4194304;             // [64,1024,64]
  unsigned short* Vtg = Kg + 4194304;             // [64,64,1024]
  unsigned short* Og  = xb;                       // alias (x consumed by then)

  cast_bf16<<<4096, 256, 0, stream>>>(x, xb, 4194304);
  transpose_cast<<<(3072 / 32) * (1024 / 32), 256, 0, stream>>>(w_attn, waT, 1024, 3072);
  transpose_cast<<<(1024 / 32) * (1024 / 32), 256, 0, stream>>>(w_proj, wpT, 1024, 1024);

  gemm_qkv256<<<16 * 12, 512, 0, stream>>>(xb, waT, b_attn, Qg, Kg, Vtg, 1024);
  attn_kernel<<<1024, 256, 0, stream>>>(Qg, Kg, Vtg, Og);
  gemm_proj128<<<32 * 8, 256, 0, stream>>>(Og, wpT, b_proj, (float*)out, 4096, 1024, 1024);
}

// Round 7
// 139.531 us; speedup vs baseline: 1.0032x; 1.0026x over previous
//
#include <hip/hip_runtime.h>
#include <hip/hip_bf16.h>

typedef __attribute__((ext_vector_type(8))) __bf16 bf16x8;
typedef __attribute__((ext_vector_type(4))) float f32x4;

__device__ __forceinline__ unsigned short f2bf(float f) {
  unsigned int u = __builtin_bit_cast(unsigned int, f);
  u += 0x7fffu + ((u >> 16) & 1u);   // RNE
  return (unsigned short)(u >> 16);
}

__device__ __forceinline__ void gll16(const void* g, void* l) {
  __builtin_amdgcn_global_load_lds(
      (const __attribute__((address_space(1))) void*)g,
      (__attribute__((address_space(3))) void*)l, 16, 0, 0);
}

// read a 16B MFMA fragment from an LDS tile with 128B rows, XOR-swizzled
__device__ __forceinline__ bf16x8 lds_frag(const unsigned short* base, int row, int kbyte) {
  int off = row * 128 + (kbyte ^ ((row & 7) << 4));
  return *(const bf16x8*)((const char*)base + off);
}

// ---------------- converts ----------------
__global__ __launch_bounds__(256) void cast_bf16(const float* __restrict__ in,
                                                 unsigned short* __restrict__ out, int n) {
  int i = (blockIdx.x * 256 + threadIdx.x) * 4;
  if (i < n) {
    float4 v = *(const float4*)(in + i);
    ushort4 o;
    o.x = f2bf(v.x); o.y = f2bf(v.y); o.z = f2bf(v.z); o.w = f2bf(v.w);
    *(ushort4*)(out + i) = o;
  }
}

// in [K][N] f32 -> out [N][K] bf16
__global__ __launch_bounds__(256) void transpose_cast(const float* __restrict__ in,
                                                      unsigned short* __restrict__ out,
                                                      int K, int N) {
  __shared__ float tile[32][33];
  int nb = N >> 5;
  int bx = blockIdx.x % nb, by = blockIdx.x / nb;
  int n0 = bx << 5, k0 = by << 5;
  int c = threadIdx.x & 31, r0 = threadIdx.x >> 5;
#pragma unroll
  for (int i = 0; i < 4; ++i) {
    int r = r0 + i * 8;
    tile[r][c] = in[(size_t)(k0 + r) * N + n0 + c];
  }
  __syncthreads();
#pragma unroll
  for (int i = 0; i < 4; ++i) {
    int r = r0 + i * 8;
    out[(size_t)(n0 + r) * K + k0 + c] = f2bf(tile[c][r]);
  }
}

// ---------------- QKV GEMM: 256x256 tile, 8 waves, STATIC double buffer ----
// C = A[4096,1024] * Bt[3072,1024]^T + bias, scattered to Q/K/Vt bf16.
// Static A0/B0/A1/B1 so alias analysis can prove stage-writes are disjoint
// from compute's ds_reads -> no compiler-injected vmcnt(0) before ds_read.
__global__ __launch_bounds__(512, 2) void gemm_qkv256(
    const unsigned short* __restrict__ A, const unsigned short* __restrict__ Bt,
    const float* __restrict__ bias,
    unsigned short* __restrict__ Qg, unsigned short* __restrict__ Kg,
    unsigned short* __restrict__ Vtg, int K) {
  __shared__ unsigned short A0[256 * 64], B0[256 * 64];
  __shared__ unsigned short A1[256 * 64], B1[256 * 64];
  const int t = threadIdx.x;
  const int l = t & 63, lr = l & 15, hi = l >> 4;
  const int w = t >> 6;
  const int wr = w >> 2, wc = w & 3;           // 2M x 4N waves
  const int bm = blockIdx.x / 12, bn = blockIdx.x % 12;
  const int m0 = bm << 8, n0 = bn << 8;
  const int wbase = (t & ~63) * 8;             // wave chunk base (ushorts)

  f32x4 acc[8][4] = {};

  auto stage = [&](int kt, unsigned short* Ad, unsigned short* Bd) {
    const unsigned short* Ab = A + (size_t)m0 * K + kt * 64;
    const unsigned short* Bb = Bt + (size_t)n0 * K + kt * 64;
#pragma unroll
    for (int i = 0; i < 4; ++i) {
      int ci = i * 512 + t;
      int row = ci >> 3, cpos = ci & 7;
      int c = cpos ^ (row & 7);                // pre-swizzled global source
      gll16(Ab + (size_t)row * K + c * 8, Ad + i * 4096 + wbase);
      gll16(Bb + (size_t)row * K + c * 8, Bd + i * 4096 + wbase);
    }
  };

  auto compute = [&](const unsigned short* Ad, const unsigned short* Bd) {
#pragma unroll
    for (int ks = 0; ks < 2; ++ks) {
      bf16x8 af[8], bv[4];
#pragma unroll
      for (int mi = 0; mi < 8; ++mi)
        af[mi] = lds_frag(Ad, wr * 128 + mi * 16 + lr, ks * 64 + hi * 16);
#pragma unroll
      for (int ni = 0; ni < 4; ++ni)
        bv[ni] = lds_frag(Bd, wc * 64 + ni * 16 + lr, ks * 64 + hi * 16);
      __builtin_amdgcn_s_setprio(1);
#pragma unroll
      for (int mi = 0; mi < 8; ++mi)
#pragma unroll
        for (int ni = 0; ni < 4; ++ni)
          acc[mi][ni] = __builtin_amdgcn_mfma_f32_16x16x32_bf16(af[mi], bv[ni], acc[mi][ni], 0, 0, 0);
      __builtin_amdgcn_s_setprio(0);
    }
  };

  const int nt = K >> 6;                       // 16
  stage(0, A0, B0);
  __syncthreads();
  for (int kt = 0; kt < nt; kt += 2) {
    if (kt + 1 < nt) stage(kt + 1, A1, B1);    // issue into buf1 (disjoint, static)
    compute(A0, B0);
    __syncthreads();                           // drains buf1 loads (issued ~full compute ago)
    if (kt + 2 < nt) stage(kt + 2, A0, B0);
    if (kt + 1 < nt) {
      compute(A1, B1);
      __syncthreads();
    }
  }

#pragma unroll
  for (int mi = 0; mi < 8; ++mi)
#pragma unroll
    for (int ni = 0; ni < 4; ++ni)
#pragma unroll
      for (int r = 0; r < 4; ++r) {
        int m = m0 + wr * 128 + mi * 16 + 4 * hi + r;
        int n = n0 + wc * 64 + ni * 16 + lr;
        float v = acc[mi][ni][r] + bias[n];
        int b = m >> 10, s = m & 1023;
        int which = n >> 10, d = n & 1023;
        int h = d >> 6, di = d & 63;
        int bh = (b << 4) + h;
        if (which == 0)      Qg[((size_t)(bh << 10) + s) * 64 + di] = f2bf(v * 0.125f);
        else if (which == 1) Kg[((size_t)(bh << 10) + s) * 64 + di] = f2bf(v);
        else                 Vtg[((size_t)(bh << 6) + di) * 1024 + s] = f2bf(v);
      }
}

// ---------------- proj GEMM: 128x128 tile, 4 waves, STATIC double buffer ----
__global__ __launch_bounds__(256) void gemm_proj128(
    const unsigned short* __restrict__ A, const unsigned short* __restrict__ Bt,
    const float* __restrict__ bias, float* __restrict__ outf,
    int M, int N, int K) {
  __shared__ unsigned short A0[128 * 64], B0[128 * 64];
  __shared__ unsigned short A1[128 * 64], B1[128 * 64];
  const int t = threadIdx.x;
  const int w = t >> 6, l = t & 63, lr = l & 15, hi = l >> 4;
  const int wr = w >> 1, wc = w & 1;
  const int nbn = N >> 7;
  const int bm = blockIdx.x / nbn, bn = blockIdx.x % nbn;
  const int m0 = bm << 7, n0 = bn << 7;
  const int wbase = (t & ~63) * 8;

  f32x4 acc[4][4] = {};

  auto stage = [&](int kt, unsigned short* Ad, unsigned short* Bd) {
    const unsigned short* Ab = A + (size_t)m0 * K + kt * 64;
    const unsigned short* Bb = Bt + (size_t)n0 * K + kt * 64;
#pragma unroll
    for (int i = 0; i < 4; ++i) {
      int ci = i * 256 + t;
      int row = ci >> 3, cpos = ci & 7;
      int c = cpos ^ (row & 7);
      gll16(Ab + (size_t)row * K + c * 8, Ad + i * 2048 + wbase);
      gll16(Bb + (size_t)row * K + c * 8, Bd + i * 2048 + wbase);
    }
  };

  auto compute = [&](const unsigned short* Ad, const unsigned short* Bd) {
#pragma unroll
    for (int ks = 0; ks < 2; ++ks) {
      bf16x8 af[4], bv[4];
#pragma unroll
      for (int mi = 0; mi < 4; ++mi)
        af[mi] = lds_frag(Ad, wr * 64 + mi * 16 + lr, ks * 64 + hi * 16);
#pragma unroll
      for (int ni = 0; ni < 4; ++ni)
        bv[ni] = lds_frag(Bd, wc * 64 + ni * 16 + lr, ks * 64 + hi * 16);
      __builtin_amdgcn_s_setprio(1);
#pragma unroll
      for (int mi = 0; mi < 4; ++mi)
#pragma unroll
        for (int ni = 0; ni < 4; ++ni)
          acc[mi][ni] = __builtin_amdgcn_mfma_f32_16x16x32_bf16(af[mi], bv[ni], acc[mi][ni], 0, 0, 0);
      __builtin_amdgcn_s_setprio(0);
    }
  };

  const int nt = K >> 6;
  stage(0, A0, B0);
  __syncthreads();
  for (int kt = 0; kt < nt; kt += 2) {
    if (kt + 1 < nt) stage(kt + 1, A1, B1);
    compute(A0, B0);
    __syncthreads();
    if (kt + 2 < nt) stage(kt + 2, A0, B0);
    if (kt + 1 < nt) {
      compute(A1, B1);
      __syncthreads();
    }
  }

#pragma unroll
  for (int mi = 0; mi < 4; ++mi)
#pragma unroll
    for (int ni = 0; ni < 4; ++ni)
#pragma unroll
      for (int r = 0; r < 4; ++r) {
        int m = m0 + wr * 64 + mi * 16 + 4 * hi + r;
        int n = n0 + wc * 64 + ni * 16 + lr;
        outf[(size_t)m * N + n] = acc[mi][ni][r] + bias[n];
      }
}

// ---------------- causal flash attention (unchanged this round) ----------------
__global__ __launch_bounds__(256) void attn_kernel(
    const unsigned short* __restrict__ Qg, const unsigned short* __restrict__ Kg,
    const unsigned short* __restrict__ Vtg, unsigned short* __restrict__ Og) {
  __shared__ unsigned short Klds[2][64 * 64];
  __shared__ unsigned short Vlds[2][64 * 64];
  __shared__ __align__(16) unsigned short Plds[4][16][72];  // padded rows: 144B
  const int bh = blockIdx.x & 63;
  const int qt = blockIdx.x >> 6;
  const int t = threadIdx.x;
  const int w = t >> 6, l = t & 63, lr = l & 15, hi = l >> 4;
  const unsigned short* Qbh = Qg + (size_t)bh * 65536;
  const unsigned short* Kbh = Kg + (size_t)bh * 65536;
  const unsigned short* Vbh = Vtg + (size_t)bh * 65536;
  const int q0 = qt * 64 + w * 16;
  const int wbase = (t & ~63) * 8;
  const float LOG2E = 1.4426950408889634f;

  bf16x8 qf[2];
#pragma unroll
  for (int ks = 0; ks < 2; ++ks)
    qf[ks] = *(const bf16x8*)(Qbh + (size_t)(q0 + lr) * 64 + ks * 32 + hi * 8);

  f32x4 oc[4] = {};
  float mrun[4], lrun[4];
#pragma unroll
  for (int r = 0; r < 4; ++r) { mrun[r] = -1e30f; lrun[r] = 0.f; }

  auto stage = [&](int kt, int b) {
#pragma unroll
    for (int i = 0; i < 2; ++i) {
      int ci = i * 256 + t;
      int row = ci >> 3, cpos = ci & 7;
      int c = cpos ^ (row & 7);
      gll16(Kbh + (size_t)(kt * 64 + row) * 64 + c * 8, &Klds[b][i * 2048 + wbase]);
      gll16(Vbh + (size_t)row * 1024 + kt * 64 + c * 8, &Vlds[b][i * 2048 + wbase]);
    }
  };

  stage(0, 0);
  __syncthreads();

  for (int kt = 0; kt <= qt; ++kt) {
    const int cur = kt & 1;
    if (kt < qt) stage(kt + 1, cur ^ 1);

    f32x4 sc[4] = {};
    __builtin_amdgcn_s_setprio(1);
#pragma unroll
    for (int c = 0; c < 4; ++c)
#pragma unroll
      for (int ks = 0; ks < 2; ++ks) {
        bf16x8 kf = lds_frag(&Klds[cur][0], c * 16 + lr, ks * 64 + hi * 16);
        sc[c] = __builtin_amdgcn_mfma_f32_16x16x32_bf16(qf[ks], kf, sc[c], 0, 0, 0);
      }
    __builtin_amdgcn_s_setprio(0);
    if (kt == qt) {
#pragma unroll
      for (int c = 0; c < 4; ++c)
#pragma unroll
        for (int r = 0; r < 4; ++r)
          if (c * 16 + lr > w * 16 + 4 * hi + r) sc[c][r] = -1e30f;
    }

    float pv[4][4];
#pragma unroll
    for (int r = 0; r < 4; ++r) {
      float mx = fmaxf(fmaxf(sc[0][r], sc[1][r]), fmaxf(sc[2][r], sc[3][r]));
#pragma unroll
      for (int d = 1; d < 16; d <<= 1) mx = fmaxf(mx, __shfl_xor(mx, d));
      float mn = fmaxf(mrun[r], mx);
      float al = exp2f((mrun[r] - mn) * LOG2E);
      mrun[r] = mn;
      float s = 0.f;
#pragma unroll
      for (int c = 0; c < 4; ++c) {
        float p = exp2f((sc[c][r] - mn) * LOG2E);
        pv[c][r] = p;
        s += p;
      }
#pragma unroll
      for (int d = 1; d < 16; d <<= 1) s += __shfl_xor(s, d);
      lrun[r] = lrun[r] * al + s;
#pragma unroll
      for (int c = 0; c < 4; ++c) oc[c][r] *= al;
    }

#pragma unroll
    for (int c = 0; c < 4; ++c)
#pragma unroll
      for (int r = 0; r < 4; ++r)
        Plds[w][4 * hi + r][c * 16 + lr] = f2bf(pv[c][r]);
    asm volatile("s_waitcnt lgkmcnt(0)" ::: "memory");
    __builtin_amdgcn_sched_barrier(0);

    bf16x8 pa[2];
#pragma unroll
    for (int ks = 0; ks < 2; ++ks)
      pa[ks] = *(const bf16x8*)(&Plds[w][lr][ks * 32 + hi * 8]);
    __builtin_amdgcn_s_setprio(1);
#pragma unroll
    for (int c = 0; c < 4; ++c)
#pragma unroll
      for (int ks = 0; ks < 2; ++ks) {
        bf16x8 vf = lds_frag(&Vlds[cur][0], c * 16 + lr, ks * 64 + hi * 16);
        oc[c] = __builtin_amdgcn_mfma_f32_16x16x32_bf16(pa[ks], vf, oc[c], 0, 0, 0);
      }
    __builtin_amdgcn_s_setprio(0);
    __syncthreads();
  }

  const int b = bh >> 4, h = bh & 15;
#pragma unroll
  for (int r = 0; r < 4; ++r) {
    float inv = 1.0f / lrun[r];
    int q = qt * 64 + w * 16 + 4 * hi + r;
    size_t rowbase = ((size_t)(b * 1024 + q)) * 1024 + h * 64;
#pragma unroll
    for (int c = 0; c < 4; ++c)
      Og[rowbase + c * 16 + lr] = f2bf(oc[c][r] * inv);
  }
}

extern "C" void kernel_launch(void* const* d_in, const int* in_sizes, int n_in,
                              void* d_out, int out_size, void* d_ws, size_t ws_size,
                              hipStream_t stream) {
  const float* x      = (const float*)d_in[0];
  const float* w_attn = (const float*)d_in[1];
  const float* b_attn = (const float*)d_in[2];
  const float* w_proj = (const float*)d_in[3];
  const float* b_proj = (const float*)d_in[4];
  float* out = (float*)d_out;

  unsigned short* ws  = (unsigned short*)d_ws;
  unsigned short* xb  = ws;                       // [4096,1024] bf16 (reused as Og)
  unsigned short* waT = xb + 4096 * 1024;         // [3072,1024] bf16
  unsigned short* wpT = waT + 3072 * 1024;        // [1024,1024] bf16
  unsigned short* Qg  = wpT + 1024 * 1024;        // [64,1024,64]
  unsigned short* Kg  = Qg + 4194304;             // [64,1024,64]
  unsigned short* Vtg = Kg + 4194304;             // [64,64,1024]
  unsigned short* Og  = xb;                       // alias (x consumed by then)

  cast_bf16<<<4096, 256, 0, stream>>>(x, xb, 4194304);
  transpose_cast<<<(3072 / 32) * (1024 / 32), 256, 0, stream>>>(w_attn, waT, 1024, 3072);
  transpose_cast<<<(1024 / 32) * (1024 / 32), 256, 0, stream>>>(w_proj, wpT, 1024, 1024);

  gemm_qkv256<<<16 * 12, 512, 0, stream>>>(xb, waT, b_attn, Qg, Kg, Vtg, 1024);
  attn_kernel<<<1024, 256, 0, stream>>>(Qg, Kg, Vtg, Og);
  gemm_proj128<<<32 * 8, 256, 0, stream>>>(Og, wpT, b_proj, (float*)out, 4096, 1024, 1024);
}